// Round 13
// baseline (700.397 us; speedup 1.0000x reference)
//
#include <hip/hip_runtime.h>

// LSTM autoencoder B=2048,T=128: L1 LSTM(128,in1) -> L2 LSTM(64,in128) -> Repeat
// -> L3 LSTM(64,in64) -> L4 LSTM(128,in64) -> Dense(1).
// R12 = R11 (bf16 activations, hi-only bf16 weights, 512 thr, RPB=16, grid=128)
// + CROSS-BARRIER WEIGHT PREFETCH: the t-loop has no global stores, so
// __syncthreads' vmcnt(0) drain is unnecessary; use `s_waitcnt lgkmcnt(0);
// s_barrier` and issue the NEXT section's A-frag loads before each barrier so
// the L2 weight stream overlaps the barrier + next section's LDS/MFMA work.
// __launch_bounds__(512,1): 256-reg budget (grid=128 -> 1 block/CU anyway).
// Arithmetic bit-identical to R11: absmax must stay exactly 7.152557e-07.

#define TSEQ 128
#define NTH  512
#define BSTR 408   // bU row stride in shorts

// LDS-only barrier: safe because the t-loop issues no global stores; global
// loads in flight (weight prefetch) may legally cross s_barrier.
#define BAR() asm volatile("s_waitcnt lgkmcnt(0)\n\ts_barrier" ::: "memory")

typedef __attribute__((ext_vector_type(8))) short bf16x8;
typedef __attribute__((ext_vector_type(4))) float f32x4;
typedef __attribute__((ext_vector_type(2))) float f32x2;
typedef __attribute__((ext_vector_type(4))) short s16x4;
typedef unsigned short ushort_t;

// frag regions in d_ws (units of 512-elem frags, 1KB each); hi even, lo odd (lo unused)
#define FB_L1 0      // U1: K=128 (KT=4), JT=32 -> 256 frags
#define FB_L2 256    // [W2;U2]: K=192 (KT=6), JT=16 -> 192
#define FB_L3 448    // U3: K=64 (KT=2), JT=16 -> 64
#define FB_L4 512    // [W4;U4]: K=192 (KT=6), JT=32 -> 384
#define FB_W3 896    // W3: K=64 (KT=2), JT=16 -> 64
#define WS_FRAGS 960
#define WS_NEEDED (WS_FRAGS * 1024)

__device__ __forceinline__ ushort_t f2bf(float f) {
    union { float f; unsigned u; } a; a.f = f;
    unsigned r = a.u + 0x7FFF + ((a.u >> 16) & 1);
    return (ushort_t)(r >> 16);
}
__device__ __forceinline__ float bf2f(ushort_t h) {
    union { unsigned u; float f; } a; a.u = ((unsigned)h) << 16;
    return a.f;
}
__device__ __forceinline__ float sigm(float z) { return 1.0f / (1.0f + __expf(-z)); }

__device__ __forceinline__ f32x4 MF(bf16x8 a, bf16x8 b, f32x4 c) {
    return __builtin_amdgcn_mfma_f32_16x16x32_bf16(a, b, c, 0, 0, 0);
}

// ---------------- weight pack kernel (unchanged layout) ----------------
__global__ void pack_weights(const float* __restrict__ U1, const float* __restrict__ W2,
                             const float* __restrict__ U2, const float* __restrict__ U3,
                             const float* __restrict__ W4, const float* __restrict__ U4,
                             const float* __restrict__ W3, ushort_t* __restrict__ out)
{
    const int f = blockIdx.x;
    const int lane = threadIdx.x;
    int fl, KT, ldm, ksplit = 1 << 30, ld2 = 0;
    const float *base, *base2 = nullptr;
    if (f < 256)      { fl = f;       KT = 4; ldm = 512; base = U1; }
    else if (f < 448) { fl = f - 256; KT = 6; ldm = 256; base = W2; ksplit = 128; base2 = U2; ld2 = 256; }
    else if (f < 512) { fl = f - 448; KT = 2; ldm = 256; base = U3; }
    else if (f < 896) { fl = f - 512; KT = 6; ldm = 512; base = W4; ksplit = 64;  base2 = U4; ld2 = 512; }
    else              { fl = f - 896; KT = 2; ldm = 256; base = W3; }
    const int jt = fl / (KT * 2);
    const int rem = fl % (KT * 2);
    const int kt = rem >> 1;
    const int s = rem & 1;
    const int j = jt * 16 + (lane & 15);
    ushort_t* o = out + f * 512 + lane * 8;
    #pragma unroll
    for (int i = 0; i < 8; ++i) {
        const int k = kt * 32 + (lane >> 4) * 8 + i;
        const float w = (k < ksplit) ? base[k * ldm + j] : base2[(k - ksplit) * ld2 + j];
        const ushort_t hi = f2bf(w);
        o[i] = s ? f2bf(w - bf2f(hi)) : hi;
    }
}

// ---------------- main kernel ----------------
__global__ __launch_bounds__(NTH, 1) void lstm_mfma_kernel(
    const float* __restrict__ x,
    const float* __restrict__ W1, const float* __restrict__ b1,
    const float* __restrict__ b2, const float* __restrict__ b3,
    const float* __restrict__ b4,
    const float* __restrict__ Wd, const float* __restrict__ bd,
    const ushort_t* __restrict__ wsp,
    float* __restrict__ out)
{
    // bU: single bf16 activation plane:
    //  phaseA: h1 ping[0,128)/pong[128,256), h2 [256,320)
    //  phaseB: h3 ping[0,64)/pong[64,128), h4 ping[128,256)/pong[256,384)
    __shared__ __align__(16) ushort_t bU[16][BSTR];      // 13056 B
    __shared__ __align__(16) float zb[16][260];          // 16640 B
    __shared__ __align__(16) float z3x[16][260];         // 16640 B
    __shared__ __align__(16) float c23[16][64];          //  4096 B
    __shared__ __align__(16) float obuf[16][128];        //  8192 B
    __shared__ __align__(16) float xls[16][132];         //  8448 B
    __shared__ __align__(16) float w1ls[512], b1ls[512], b4ls[512], b2ls[256];

    const int tid  = threadIdx.x;
    const int wid  = tid >> 6;
    const int lane = tid & 63;
    const int quad = lane >> 4;
    const int l15  = lane & 15;
    const int r0   = blockIdx.x * 16;
    const bf16x8* A = (const bf16x8*)wsp;

    // gate-section mapping: thread owns row rg and 2 adjacent cols jp, jp+1
    const int rg = tid >> 5;
    const int jp = (tid & 31) * 2;

    // ---- init: zero state, stage x / W1 / biases ----
    {
        unsigned* p = (unsigned*)&bU[0][0];
        for (int i = tid; i < 16 * BSTR / 2; i += NTH) p[i] = 0u;
        float* q = &c23[0][0];
        for (int i = tid; i < 16 * 64; i += NTH) q[i] = 0.f;
        const int srow = tid >> 5, scol = (tid & 31) * 4;
        *(f32x4*)&xls[srow][scol] = *(const f32x4*)&x[(r0 + srow) * TSEQ + scol];
        w1ls[tid] = W1[tid];
        b1ls[tid] = b1[tid];
        b4ls[tid] = b4[tid];
        if (tid < 256) b2ls[tid] = b2[tid];
    }

    const int hcb = 16 * wid + quad * 4;   // j base within gate for 512-wide layers
    const float wd0 = Wd[lane], wd1 = Wd[64 + lane], bd0 = bd[0];

    float c1r[4] = {0.f, 0.f, 0.f, 0.f};
    float c4r[4] = {0.f, 0.f, 0.f, 0.f};

    // prologue prefetch: L1 frags for t=0
    bf16x8 pf1[16];
    #pragma unroll
    for (int q = 0; q < 4; ++q)
        #pragma unroll
        for (int kt = 0; kt < 4; ++kt)
            pf1[q * 4 + kt] = A[(FB_L1 + ((wid + 8 * q) * 4 + kt) * 2) * 64 + lane];

    __syncthreads();

    // ================= Phase A =================
    for (int t = 0; t < TSEQ; ++t) {
        const int rb1 = (t & 1) * 128, wb1 = 128 - rb1;
        bf16x8 pf2[12];

        // ---- L1: MFMA (acc init = b1 + x*W1) + in-register gates ----
        {
            bf16x8 Bh[4];
            #pragma unroll
            for (int kt = 0; kt < 4; ++kt)
                Bh[kt] = *(const bf16x8*)&bU[l15][rb1 + kt * 32 + quad * 8];
            const float xr = xls[l15][t];
            f32x4 acc[4];
            #pragma unroll
            for (int q = 0; q < 4; ++q) {
                const int jb = (wid + 8 * q) * 16 + quad * 4;
                f32x4 a = *(const f32x4*)&b1ls[jb];
                a += xr * *(const f32x4*)&w1ls[jb];
                #pragma unroll
                for (int kt = 0; kt < 4; ++kt)
                    a = MF(pf1[q * 4 + kt], Bh[kt], a);
                acc[q] = a;
            }
            // prefetch L2's A-frags: in flight across the barrier
            #pragma unroll
            for (int jj = 0; jj < 2; ++jj)
                #pragma unroll
                for (int kt = 0; kt < 6; ++kt)
                    pf2[jj * 6 + kt] = A[(FB_L2 + ((2 * wid + jj) * 6 + kt) * 2) * 64 + lane];
            s16x4 hv;
            #pragma unroll
            for (int g = 0; g < 4; ++g) {
                const float zi = acc[0][g];
                const float zf = acc[1][g];
                const float zg = acc[2][g];
                const float zo = acc[3][g];
                const float c = sigm(zf) * c1r[g] + sigm(zi) * fmaxf(zg, 0.f);
                c1r[g] = c;
                const float h = sigm(zo) * fmaxf(c, 0.f);
                hv[g] = (short)f2bf(h);
            }
            *(s16x4*)&bU[l15][wb1 + hcb] = hv;
        }
        BAR();

        // ---- L2 MFMA: K=192 = [h1_new ; h2_old], acc init = b2 ----
        {
            bf16x8 Bh[6];
            #pragma unroll
            for (int kt = 0; kt < 4; ++kt)
                Bh[kt] = *(const bf16x8*)&bU[l15][wb1 + kt * 32 + quad * 8];
            #pragma unroll
            for (int kt = 4; kt < 6; ++kt)
                Bh[kt] = *(const bf16x8*)&bU[l15][256 + (kt - 4) * 32 + quad * 8];
            #pragma unroll
            for (int jj = 0; jj < 2; ++jj) {
                const int jt = 2 * wid + jj;
                f32x4 a = *(const f32x4*)&b2ls[jt * 16 + quad * 4];
                #pragma unroll
                for (int kt = 0; kt < 6; ++kt)
                    a = MF(pf2[jj * 6 + kt], Bh[kt], a);
                *(f32x4*)&zb[l15][jt * 16 + quad * 4] = a;
            }
            // prefetch L1's A-frags for t+1: in flight across the barrier
            #pragma unroll
            for (int q = 0; q < 4; ++q)
                #pragma unroll
                for (int kt = 0; kt < 4; ++kt)
                    pf1[q * 4 + kt] = A[(FB_L1 + ((wid + 8 * q) * 4 + kt) * 2) * 64 + lane];
        }
        BAR();

        // ---- L2 gates: thread = (row rg, cols jp,jp+1); b32 store ----
        {
            const f32x2 zi = *(const f32x2*)&zb[rg][jp];
            const f32x2 zf = *(const f32x2*)&zb[rg][64 + jp];
            const f32x2 zg = *(const f32x2*)&zb[rg][128 + jp];
            const f32x2 zo = *(const f32x2*)&zb[rg][192 + jp];
            f32x2 c = *(const f32x2*)&c23[rg][jp];
            unsigned hw = 0;
            #pragma unroll
            for (int k = 0; k < 2; ++k) {
                const float cc = sigm(zf[k]) * c[k] + sigm(zi[k]) * fmaxf(zg[k], 0.f);
                c[k] = cc;
                const float h = sigm(zo[k]) * fmaxf(cc, 0.f);
                hw |= ((unsigned)f2bf(h)) << (16 * k);
            }
            *(f32x2*)&c23[rg][jp] = c;
            *(unsigned*)&bU[rg][256 + jp] = hw;
        }
        // no trailing barrier: next-iter BAR1 covers hazards
    }
    __syncthreads();

    // ================= z3x = b3 + h2_final @ W3 (K=64 at col 256) =================
    {
        bf16x8 Bh[2];
        #pragma unroll
        for (int kt = 0; kt < 2; ++kt)
            Bh[kt] = *(const bf16x8*)&bU[l15][256 + kt * 32 + quad * 8];
        #pragma unroll
        for (int jj = 0; jj < 2; ++jj) {
            const int jt = 2 * wid + jj;
            f32x4 a = *(const f32x4*)&b3[jt * 16 + quad * 4];
            #pragma unroll
            for (int kt = 0; kt < 2; ++kt) {
                const bf16x8 ah = A[(FB_W3 + (jt * 2 + kt) * 2) * 64 + lane];
                a = MF(ah, Bh[kt], a);
            }
            *(f32x4*)&z3x[l15][jt * 16 + quad * 4] = a;
        }
    }
    __syncthreads();
    // re-zero activation plane + c-state for phase B
    {
        unsigned* p = (unsigned*)&bU[0][0];
        for (int i = tid; i < 16 * BSTR / 2; i += NTH) p[i] = 0u;
        float* q = &c23[0][0];
        for (int i = tid; i < 16 * 64; i += NTH) q[i] = 0.f;
        c4r[0] = c4r[1] = c4r[2] = c4r[3] = 0.f;
    }
    // prologue prefetch: L3 frags for t=0
    bf16x8 pf3[4];
    #pragma unroll
    for (int jj = 0; jj < 2; ++jj)
        #pragma unroll
        for (int kt = 0; kt < 2; ++kt)
            pf3[jj * 2 + kt] = A[(FB_L3 + ((2 * wid + jj) * 2 + kt) * 2) * 64 + lane];
    __syncthreads();

    // ================= Phase B =================
    for (int t = 0; t < TSEQ; ++t) {
        const int rb3 = (t & 1) * 64, wb3 = 64 - rb3;
        const int rb4 = 128 + (t & 1) * 128;
        const int wb4 = (rb4 == 128) ? 256 : 128;
        bf16x8 pf4[24];

        // ---- L3 MFMA (h3_old), acc init = 0 (z3x carries b3) ----
        {
            bf16x8 Bh[2];
            #pragma unroll
            for (int kt = 0; kt < 2; ++kt)
                Bh[kt] = *(const bf16x8*)&bU[l15][rb3 + kt * 32 + quad * 8];
            #pragma unroll
            for (int jj = 0; jj < 2; ++jj) {
                const int jt = 2 * wid + jj;
                f32x4 a = {0.f, 0.f, 0.f, 0.f};
                #pragma unroll
                for (int kt = 0; kt < 2; ++kt)
                    a = MF(pf3[jj * 2 + kt], Bh[kt], a);
                *(f32x4*)&zb[l15][jt * 16 + quad * 4] = a;
            }
            // prefetch L4's A-frags: in flight across two barriers
            #pragma unroll
            for (int q = 0; q < 4; ++q)
                #pragma unroll
                for (int kt = 0; kt < 6; ++kt)
                    pf4[q * 6 + kt] = A[(FB_L4 + ((wid + 8 * q) * 6 + kt) * 2) * 64 + lane];
        }
        BAR();

        // ---- L3 gates (z = zb + z3x) + dense(t-1) into obuf ----
        {
            const f32x2 zi = *(const f32x2*)&zb[rg][jp]       + *(const f32x2*)&z3x[rg][jp];
            const f32x2 zf = *(const f32x2*)&zb[rg][64 + jp]  + *(const f32x2*)&z3x[rg][64 + jp];
            const f32x2 zg = *(const f32x2*)&zb[rg][128 + jp] + *(const f32x2*)&z3x[rg][128 + jp];
            const f32x2 zo = *(const f32x2*)&zb[rg][192 + jp] + *(const f32x2*)&z3x[rg][192 + jp];
            f32x2 c = *(const f32x2*)&c23[rg][jp];
            unsigned hw = 0;
            #pragma unroll
            for (int k = 0; k < 2; ++k) {
                const float cc = sigm(zf[k]) * c[k] + sigm(zi[k]) * fmaxf(zg[k], 0.f);
                c[k] = cc;
                const float h = sigm(zo[k]) * fmaxf(cc, 0.f);
                hw |= ((unsigned)f2bf(h)) << (16 * k);
            }
            *(f32x2*)&c23[rg][jp] = c;
            *(unsigned*)&bU[rg][wb3 + jp] = hw;

            if (t > 0) {  // dense for t-1: h4_{t-1} at rb4 (protected by BAR1)
                #pragma unroll
                for (int e = 0; e < 2; ++e) {
                    const int r = wid + 8 * e;
                    const float h0 = bf2f(bU[r][rb4 + lane]);
                    const float h1_ = bf2f(bU[r][rb4 + 64 + lane]);
                    float v = h0 * wd0 + h1_ * wd1;
                    v += __shfl_down(v, 32);
                    v += __shfl_down(v, 16);
                    v += __shfl_down(v, 8);
                    v += __shfl_down(v, 4);
                    v += __shfl_down(v, 2);
                    v += __shfl_down(v, 1);
                    if (lane == 0) obuf[r][t - 1] = v + bd0;
                }
            }
        }
        BAR();

        // ---- L4: MFMA K=192 = [h3_new ; h4_old], acc init = b4; in-register gates ----
        {
            bf16x8 Bh[6];
            #pragma unroll
            for (int kt = 0; kt < 2; ++kt)
                Bh[kt] = *(const bf16x8*)&bU[l15][wb3 + kt * 32 + quad * 8];
            #pragma unroll
            for (int kt = 2; kt < 6; ++kt)
                Bh[kt] = *(const bf16x8*)&bU[l15][rb4 + (kt - 2) * 32 + quad * 8];
            f32x4 acc[4];
            #pragma unroll
            for (int q = 0; q < 4; ++q) {
                f32x4 a = *(const f32x4*)&b4ls[(wid + 8 * q) * 16 + quad * 4];
                #pragma unroll
                for (int kt = 0; kt < 6; ++kt)
                    a = MF(pf4[q * 6 + kt], Bh[kt], a);
                acc[q] = a;
            }
            // prefetch L3's A-frags for t+1
            #pragma unroll
            for (int jj = 0; jj < 2; ++jj)
                #pragma unroll
                for (int kt = 0; kt < 2; ++kt)
                    pf3[jj * 2 + kt] = A[(FB_L3 + ((2 * wid + jj) * 2 + kt) * 2) * 64 + lane];
            s16x4 hv;
            #pragma unroll
            for (int g = 0; g < 4; ++g) {
                const float zi = acc[0][g];
                const float zf = acc[1][g];
                const float zg = acc[2][g];
                const float zo = acc[3][g];
                const float c = sigm(zf) * c4r[g] + sigm(zi) * fmaxf(zg, 0.f);
                c4r[g] = c;
                const float h = sigm(zo) * fmaxf(c, 0.f);
                hv[g] = (short)f2bf(h);
            }
            *(s16x4*)&bU[l15][wb4 + hcb] = hv;
        }
        // no trailing barrier: next-iter BAR1 covers h4/zb hazards
    }
    __syncthreads();
    // final dense: h4_{127} at col 128 (wb4 of t=127) -> obuf
    {
        #pragma unroll
        for (int e = 0; e < 2; ++e) {
            const int r = wid + 8 * e;
            const float h0 = bf2f(bU[r][128 + lane]);
            const float h1_ = bf2f(bU[r][128 + 64 + lane]);
            float v = h0 * wd0 + h1_ * wd1;
            v += __shfl_down(v, 32);
            v += __shfl_down(v, 16);
            v += __shfl_down(v, 8);
            v += __shfl_down(v, 4);
            v += __shfl_down(v, 2);
            v += __shfl_down(v, 1);
            if (lane == 0) obuf[r][127] = v + bd0;
        }
    }
    __syncthreads();
    // coalesced flush: 4 floats/thread
    {
        const int frow = tid >> 5;
        const int fcol = (tid & 31) * 4;
        *(f32x4*)&out[(r0 + frow) * TSEQ + fcol] = *(const f32x4*)&obuf[frow][fcol];
    }
}

// ---------------- fallback: round-0 fp32 kernel (known good, 4.8 ms) ----------------
#define FNT 512
#define FRPB 8
__global__ __launch_bounds__(FNT, 2) void lstm_stack_kernel(
    const float* __restrict__ x,
    const float* __restrict__ W1, const float* __restrict__ U1, const float* __restrict__ b1,
    const float* __restrict__ W2, const float* __restrict__ U2, const float* __restrict__ b2,
    const float* __restrict__ W3, const float* __restrict__ U3, const float* __restrict__ b3,
    const float* __restrict__ W4, const float* __restrict__ U4, const float* __restrict__ b4,
    const float* __restrict__ Wd, const float* __restrict__ bd,
    float* __restrict__ out)
{
    __shared__ float h1s[FRPB][128], c1s[FRPB][128];
    __shared__ float h2s[FRPB][64],  c2s[FRPB][64];
    __shared__ float h3s[FRPB][64],  c3s[FRPB][64];
    __shared__ float h4s[FRPB][128], c4s[FRPB][128];
    __shared__ float zbf[FRPB][512];
    __shared__ float z3xf[FRPB][256];
    __shared__ float xs[FRPB];

    const int tid = threadIdx.x;
    const int r0  = blockIdx.x * FRPB;
    const int jg  = tid & 255;
    const int grp = tid >> 8;
    const int rb  = grp * 4;

    {
        float* p1 = &h1s[0][0]; float* p2 = &c1s[0][0];
        float* p3 = &h4s[0][0]; float* p4 = &c4s[0][0];
        for (int i = tid; i < FRPB * 128; i += FNT) { p1[i]=0.f; p2[i]=0.f; p3[i]=0.f; p4[i]=0.f; }
        float* q1 = &h2s[0][0]; float* q2 = &c2s[0][0];
        float* q3 = &h3s[0][0]; float* q4 = &c3s[0][0];
        for (int i = tid; i < FRPB * 64; i += FNT) { q1[i]=0.f; q2[i]=0.f; q3[i]=0.f; q4[i]=0.f; }
    }
    __syncthreads();

    const float w1j = W1[tid];
    const float b1j = b1[tid];
    const float b2j = b2[jg];

    for (int t = 0; t < TSEQ; ++t) {
        if (tid < FRPB) xs[tid] = x[(r0 + tid) * TSEQ + t];
        __syncthreads();
        {
            float acc[FRPB];
            #pragma unroll
            for (int r = 0; r < FRPB; ++r) acc[r] = 0.f;
            const float* Uc = U1 + tid;
            #pragma unroll 4
            for (int k4 = 0; k4 < 32; ++k4) {
                const float u0 = Uc[(k4*4+0)*512];
                const float u1 = Uc[(k4*4+1)*512];
                const float u2 = Uc[(k4*4+2)*512];
                const float u3 = Uc[(k4*4+3)*512];
                #pragma unroll
                for (int r = 0; r < FRPB; ++r) {
                    const float4 h = ((const float4*)h1s[r])[k4];
                    acc[r] += h.x*u0 + h.y*u1 + h.z*u2 + h.w*u3;
                }
            }
            #pragma unroll
            for (int r = 0; r < FRPB; ++r) zbf[r][tid] = acc[r] + xs[r]*w1j + b1j;
        }
        __syncthreads();
        for (int e = tid; e < FRPB * 128; e += FNT) {
            const int r = e >> 7, hc = e & 127;
            const float zi = zbf[r][hc], zf = zbf[r][128+hc], zg = zbf[r][256+hc], zo = zbf[r][384+hc];
            const float c = sigm(zf)*c1s[r][hc] + sigm(zi)*fmaxf(zg, 0.f);
            c1s[r][hc] = c;
            h1s[r][hc] = sigm(zo)*fmaxf(c, 0.f);
        }
        __syncthreads();
        {
            float acc[4] = {0.f, 0.f, 0.f, 0.f};
            const float* Wc = W2 + jg;
            #pragma unroll 4
            for (int k4 = 0; k4 < 32; ++k4) {
                const float u0 = Wc[(k4*4+0)*256];
                const float u1 = Wc[(k4*4+1)*256];
                const float u2 = Wc[(k4*4+2)*256];
                const float u3 = Wc[(k4*4+3)*256];
                #pragma unroll
                for (int q = 0; q < 4; ++q) {
                    const float4 h = ((const float4*)h1s[rb+q])[k4];
                    acc[q] += h.x*u0 + h.y*u1 + h.z*u2 + h.w*u3;
                }
            }
            const float* Uc = U2 + jg;
            #pragma unroll 4
            for (int k4 = 0; k4 < 16; ++k4) {
                const float u0 = Uc[(k4*4+0)*256];
                const float u1 = Uc[(k4*4+1)*256];
                const float u2 = Uc[(k4*4+2)*256];
                const float u3 = Uc[(k4*4+3)*256];
                #pragma unroll
                for (int q = 0; q < 4; ++q) {
                    const float4 h = ((const float4*)h2s[rb+q])[k4];
                    acc[q] += h.x*u0 + h.y*u1 + h.z*u2 + h.w*u3;
                }
            }
            #pragma unroll
            for (int q = 0; q < 4; ++q) zbf[rb+q][jg] = acc[q] + b2j;
        }
        __syncthreads();
        {
            const int r = tid >> 6, hc = tid & 63;
            const float zi = zbf[r][hc], zf = zbf[r][64+hc], zg = zbf[r][128+hc], zo = zbf[r][192+hc];
            const float c = sigm(zf)*c2s[r][hc] + sigm(zi)*fmaxf(zg, 0.f);
            c2s[r][hc] = c;
            h2s[r][hc] = sigm(zo)*fmaxf(c, 0.f);
        }
        __syncthreads();
    }
    {
        float acc[4] = {0.f, 0.f, 0.f, 0.f};
        const float* Wc = W3 + jg;
        #pragma unroll 4
        for (int k4 = 0; k4 < 16; ++k4) {
            const float u0 = Wc[(k4*4+0)*256];
            const float u1 = Wc[(k4*4+1)*256];
            const float u2 = Wc[(k4*4+2)*256];
            const float u3 = Wc[(k4*4+3)*256];
            #pragma unroll
            for (int q = 0; q < 4; ++q) {
                const float4 h = ((const float4*)h2s[rb+q])[k4];
                acc[q] += h.x*u0 + h.y*u1 + h.z*u2 + h.w*u3;
            }
        }
        const float b3j = b3[jg];
        #pragma unroll
        for (int q = 0; q < 4; ++q) z3xf[rb+q][jg] = acc[q] + b3j;
    }
    __syncthreads();

    const float b4j = b4[tid];
    const float wd0 = Wd[tid & 63];
    const float wd1 = Wd[64 + (tid & 63)];
    const float bd0 = bd[0];

    for (int t = 0; t < TSEQ; ++t) {
        {
            float acc[4];
            #pragma unroll
            for (int q = 0; q < 4; ++q) acc[q] = z3xf[rb+q][jg];
            const float* Uc = U3 + jg;
            #pragma unroll 4
            for (int k4 = 0; k4 < 16; ++k4) {
                const float u0 = Uc[(k4*4+0)*256];
                const float u1 = Uc[(k4*4+1)*256];
                const float u2 = Uc[(k4*4+2)*256];
                const float u3 = Uc[(k4*4+3)*256];
                #pragma unroll
                for (int q = 0; q < 4; ++q) {
                    const float4 h = ((const float4*)h3s[rb+q])[k4];
                    acc[q] += h.x*u0 + h.y*u1 + h.z*u2 + h.w*u3;
                }
            }
            #pragma unroll
            for (int q = 0; q < 4; ++q) zbf[rb+q][jg] = acc[q];
        }
        __syncthreads();
        {
            const int r = tid >> 6, hc = tid & 63;
            const float zi = zbf[r][hc], zf = zbf[r][64+hc], zg = zbf[r][128+hc], zo = zbf[r][192+hc];
            const float c = sigm(zf)*c3s[r][hc] + sigm(zi)*fmaxf(zg, 0.f);
            c3s[r][hc] = c;
            h3s[r][hc] = sigm(zo)*fmaxf(c, 0.f);
        }
        __syncthreads();
        {
            float acc[FRPB];
            #pragma unroll
            for (int r = 0; r < FRPB; ++r) acc[r] = 0.f;
            const float* Wc = W4 + tid;
            #pragma unroll 4
            for (int k4 = 0; k4 < 16; ++k4) {
                const float u0 = Wc[(k4*4+0)*512];
                const float u1 = Wc[(k4*4+1)*512];
                const float u2 = Wc[(k4*4+2)*512];
                const float u3 = Wc[(k4*4+3)*512];
                #pragma unroll
                for (int r = 0; r < FRPB; ++r) {
                    const float4 h = ((const float4*)h3s[r])[k4];
                    acc[r] += h.x*u0 + h.y*u1 + h.z*u2 + h.w*u3;
                }
            }
            const float* Uc = U4 + tid;
            #pragma unroll 4
            for (int k4 = 0; k4 < 32; ++k4) {
                const float u0 = Uc[(k4*4+0)*512];
                const float u1 = Uc[(k4*4+1)*512];
                const float u2 = Uc[(k4*4+2)*512];
                const float u3 = Uc[(k4*4+3)*512];
                #pragma unroll
                for (int r = 0; r < FRPB; ++r) {
                    const float4 h = ((const float4*)h4s[r])[k4];
                    acc[r] += h.x*u0 + h.y*u1 + h.z*u2 + h.w*u3;
                }
            }
            #pragma unroll
            for (int r = 0; r < FRPB; ++r) zbf[r][tid] = acc[r] + b4j;
        }
        __syncthreads();
        for (int e = tid; e < FRPB * 128; e += FNT) {
            const int r = e >> 7, hc = e & 127;
            const float zi = zbf[r][hc], zf = zbf[r][128+hc], zg = zbf[r][256+hc], zo = zbf[r][384+hc];
            const float c = sigm(zf)*c4s[r][hc] + sigm(zi)*fmaxf(zg, 0.f);
            c4s[r][hc] = c;
            h4s[r][hc] = sigm(zo)*fmaxf(c, 0.f);
        }
        __syncthreads();
        {
            const int wv = tid >> 6, ln = tid & 63;
            float v = h4s[wv][ln]*wd0 + h4s[wv][64+ln]*wd1;
            v += __shfl_down(v, 32, 64);
            v += __shfl_down(v, 16, 64);
            v += __shfl_down(v,  8, 64);
            v += __shfl_down(v,  4, 64);
            v += __shfl_down(v,  2, 64);
            v += __shfl_down(v,  1, 64);
            if (ln == 0) out[(r0 + wv) * TSEQ + t] = v + bd0;
        }
    }
}

extern "C" void kernel_launch(void* const* d_in, const int* in_sizes, int n_in,
                              void* d_out, int out_size, void* d_ws, size_t ws_size,
                              hipStream_t stream) {
    const float* x  = (const float*)d_in[0];
    const float* W1 = (const float*)d_in[1];
    const float* U1 = (const float*)d_in[2];
    const float* b1 = (const float*)d_in[3];
    const float* W2 = (const float*)d_in[4];
    const float* U2 = (const float*)d_in[5];
    const float* b2 = (const float*)d_in[6];
    const float* W3 = (const float*)d_in[7];
    const float* U3 = (const float*)d_in[8];
    const float* b3 = (const float*)d_in[9];
    const float* W4 = (const float*)d_in[10];
    const float* U4 = (const float*)d_in[11];
    const float* b4 = (const float*)d_in[12];
    const float* Wd = (const float*)d_in[13];
    const float* bd = (const float*)d_in[14];
    float* out = (float*)d_out;

    if (ws_size >= (size_t)WS_NEEDED) {
        ushort_t* wsp = (ushort_t*)d_ws;
        pack_weights<<<dim3(WS_FRAGS), dim3(64), 0, stream>>>(U1, W2, U2, U3, W4, U4, W3, wsp);
        lstm_mfma_kernel<<<dim3(2048 / 16), dim3(NTH), 0, stream>>>(
            x, W1, b1, b2, b3, b4, Wd, bd, wsp, out);
    } else {
        lstm_stack_kernel<<<dim3(2048 / FRPB), dim3(FNT), 0, stream>>>(
            x, W1, U1, b1, W2, U2, b2, W3, U3, b3, W4, U4, b4, Wd, bd, out);
    }
}

// Round 14
// 611.291 us; speedup vs baseline: 1.1458x; 1.1458x over previous
//
#include <hip/hip_runtime.h>

// LSTM autoencoder B=2048,T=128: L1 LSTM(128,in1) -> L2 LSTM(64,in128) -> Repeat
// -> L3 LSTM(64,in64) -> L4 LSTM(128,in64) -> Dense(1).
// R13 = exact revert to R11 (best verified: 614us total / 562us kernel).
// R11: bf16 activations (single plane), hi-only bf16 weights streamed from L2,
// 512 thr, RPB=16, grid=128, 2 barriers/t, fp32 c-state and z.
// R12's cross-barrier prefetch (asm barrier + memory clobber) REGRESSED +18%:
// the clobber invalidated compiler-cached loop-invariant LDS reads. Scheduling
// interventions are triple-falsified (R9/R10/R12); byte reductions are
// accuracy-capped (margin 1.66x). This structure is the practical plateau.

#define TSEQ 128
#define NTH  512
#define BSTR 408   // bU row stride in shorts

typedef __attribute__((ext_vector_type(8))) short bf16x8;
typedef __attribute__((ext_vector_type(4))) float f32x4;
typedef __attribute__((ext_vector_type(2))) float f32x2;
typedef __attribute__((ext_vector_type(4))) short s16x4;
typedef unsigned short ushort_t;

// frag regions in d_ws (units of 512-elem frags, 1KB each); hi even, lo odd (lo unused)
#define FB_L1 0      // U1: K=128 (KT=4), JT=32 -> 256 frags
#define FB_L2 256    // [W2;U2]: K=192 (KT=6), JT=16 -> 192
#define FB_L3 448    // U3: K=64 (KT=2), JT=16 -> 64
#define FB_L4 512    // [W4;U4]: K=192 (KT=6), JT=32 -> 384
#define FB_W3 896    // W3: K=64 (KT=2), JT=16 -> 64
#define WS_FRAGS 960
#define WS_NEEDED (WS_FRAGS * 1024)

__device__ __forceinline__ ushort_t f2bf(float f) {
    union { float f; unsigned u; } a; a.f = f;
    unsigned r = a.u + 0x7FFF + ((a.u >> 16) & 1);
    return (ushort_t)(r >> 16);
}
__device__ __forceinline__ float bf2f(ushort_t h) {
    union { unsigned u; float f; } a; a.u = ((unsigned)h) << 16;
    return a.f;
}
__device__ __forceinline__ float sigm(float z) { return 1.0f / (1.0f + __expf(-z)); }

__device__ __forceinline__ f32x4 MF(bf16x8 a, bf16x8 b, f32x4 c) {
    return __builtin_amdgcn_mfma_f32_16x16x32_bf16(a, b, c, 0, 0, 0);
}

// ---------------- weight pack kernel (unchanged layout) ----------------
__global__ void pack_weights(const float* __restrict__ U1, const float* __restrict__ W2,
                             const float* __restrict__ U2, const float* __restrict__ U3,
                             const float* __restrict__ W4, const float* __restrict__ U4,
                             const float* __restrict__ W3, ushort_t* __restrict__ out)
{
    const int f = blockIdx.x;
    const int lane = threadIdx.x;
    int fl, KT, ldm, ksplit = 1 << 30, ld2 = 0;
    const float *base, *base2 = nullptr;
    if (f < 256)      { fl = f;       KT = 4; ldm = 512; base = U1; }
    else if (f < 448) { fl = f - 256; KT = 6; ldm = 256; base = W2; ksplit = 128; base2 = U2; ld2 = 256; }
    else if (f < 512) { fl = f - 448; KT = 2; ldm = 256; base = U3; }
    else if (f < 896) { fl = f - 512; KT = 6; ldm = 512; base = W4; ksplit = 64;  base2 = U4; ld2 = 512; }
    else              { fl = f - 896; KT = 2; ldm = 256; base = W3; }
    const int jt = fl / (KT * 2);
    const int rem = fl % (KT * 2);
    const int kt = rem >> 1;
    const int s = rem & 1;
    const int j = jt * 16 + (lane & 15);
    ushort_t* o = out + f * 512 + lane * 8;
    #pragma unroll
    for (int i = 0; i < 8; ++i) {
        const int k = kt * 32 + (lane >> 4) * 8 + i;
        const float w = (k < ksplit) ? base[k * ldm + j] : base2[(k - ksplit) * ld2 + j];
        const ushort_t hi = f2bf(w);
        o[i] = s ? f2bf(w - bf2f(hi)) : hi;
    }
}

// ---------------- main kernel ----------------
__global__ __launch_bounds__(NTH, 2) void lstm_mfma_kernel(
    const float* __restrict__ x,
    const float* __restrict__ W1, const float* __restrict__ b1,
    const float* __restrict__ b2, const float* __restrict__ b3,
    const float* __restrict__ b4,
    const float* __restrict__ Wd, const float* __restrict__ bd,
    const ushort_t* __restrict__ wsp,
    float* __restrict__ out)
{
    // bU: single bf16 activation plane:
    //  phaseA: h1 ping[0,128)/pong[128,256), h2 [256,320)
    //  phaseB: h3 ping[0,64)/pong[64,128), h4 ping[128,256)/pong[256,384)
    __shared__ __align__(16) ushort_t bU[16][BSTR];      // 13056 B
    __shared__ __align__(16) float zb[16][260];          // 16640 B
    __shared__ __align__(16) float z3x[16][260];         // 16640 B
    __shared__ __align__(16) float c23[16][64];          //  4096 B
    __shared__ __align__(16) float obuf[16][128];        //  8192 B
    __shared__ __align__(16) float xls[16][132];         //  8448 B
    __shared__ __align__(16) float w1ls[512], b1ls[512], b4ls[512], b2ls[256];

    const int tid  = threadIdx.x;
    const int wid  = tid >> 6;
    const int lane = tid & 63;
    const int quad = lane >> 4;
    const int l15  = lane & 15;
    const int r0   = blockIdx.x * 16;
    const bf16x8* A = (const bf16x8*)wsp;

    // gate-section mapping: thread owns row rg and 2 adjacent cols jp, jp+1
    const int rg = tid >> 5;
    const int jp = (tid & 31) * 2;

    // ---- init: zero state, stage x / W1 / biases ----
    {
        unsigned* p = (unsigned*)&bU[0][0];
        for (int i = tid; i < 16 * BSTR / 2; i += NTH) p[i] = 0u;
        float* q = &c23[0][0];
        for (int i = tid; i < 16 * 64; i += NTH) q[i] = 0.f;
        const int srow = tid >> 5, scol = (tid & 31) * 4;
        *(f32x4*)&xls[srow][scol] = *(const f32x4*)&x[(r0 + srow) * TSEQ + scol];
        w1ls[tid] = W1[tid];
        b1ls[tid] = b1[tid];
        b4ls[tid] = b4[tid];
        if (tid < 256) b2ls[tid] = b2[tid];
    }

    const int hcb = 16 * wid + quad * 4;   // j base within gate for 512-wide layers
    const float wd0 = Wd[lane], wd1 = Wd[64 + lane], bd0 = bd[0];

    float c1r[4] = {0.f, 0.f, 0.f, 0.f};
    float c4r[4] = {0.f, 0.f, 0.f, 0.f};

    __syncthreads();

    // ================= Phase A =================
    for (int t = 0; t < TSEQ; ++t) {
        const int rb1 = (t & 1) * 128, wb1 = 128 - rb1;

        // ---- L1: MFMA (acc init = b1 + x*W1) + in-register gates ----
        {
            bf16x8 ah[16];
            #pragma unroll
            for (int q = 0; q < 4; ++q)
                #pragma unroll
                for (int kt = 0; kt < 4; ++kt)
                    ah[q * 4 + kt] = A[(FB_L1 + ((wid + 8 * q) * 4 + kt) * 2) * 64 + lane];
            bf16x8 Bh[4];
            #pragma unroll
            for (int kt = 0; kt < 4; ++kt)
                Bh[kt] = *(const bf16x8*)&bU[l15][rb1 + kt * 32 + quad * 8];
            const float xr = xls[l15][t];
            f32x4 acc[4];
            #pragma unroll
            for (int q = 0; q < 4; ++q) {
                const int jb = (wid + 8 * q) * 16 + quad * 4;
                f32x4 a = *(const f32x4*)&b1ls[jb];
                a += xr * *(const f32x4*)&w1ls[jb];
                #pragma unroll
                for (int kt = 0; kt < 4; ++kt)
                    a = MF(ah[q * 4 + kt], Bh[kt], a);
                acc[q] = a;
            }
            s16x4 hv;
            #pragma unroll
            for (int g = 0; g < 4; ++g) {
                const float zi = acc[0][g];
                const float zf = acc[1][g];
                const float zg = acc[2][g];
                const float zo = acc[3][g];
                const float c = sigm(zf) * c1r[g] + sigm(zi) * fmaxf(zg, 0.f);
                c1r[g] = c;
                const float h = sigm(zo) * fmaxf(c, 0.f);
                hv[g] = (short)f2bf(h);
            }
            *(s16x4*)&bU[l15][wb1 + hcb] = hv;
        }
        __syncthreads();

        // ---- L2 MFMA: K=192 = [h1_new ; h2_old], acc init = b2 ----
        {
            bf16x8 ah[12];
            #pragma unroll
            for (int jj = 0; jj < 2; ++jj)
                #pragma unroll
                for (int kt = 0; kt < 6; ++kt)
                    ah[jj * 6 + kt] = A[(FB_L2 + ((2 * wid + jj) * 6 + kt) * 2) * 64 + lane];
            bf16x8 Bh[6];
            #pragma unroll
            for (int kt = 0; kt < 4; ++kt)
                Bh[kt] = *(const bf16x8*)&bU[l15][wb1 + kt * 32 + quad * 8];
            #pragma unroll
            for (int kt = 4; kt < 6; ++kt)
                Bh[kt] = *(const bf16x8*)&bU[l15][256 + (kt - 4) * 32 + quad * 8];
            #pragma unroll
            for (int jj = 0; jj < 2; ++jj) {
                const int jt = 2 * wid + jj;
                f32x4 a = *(const f32x4*)&b2ls[jt * 16 + quad * 4];
                #pragma unroll
                for (int kt = 0; kt < 6; ++kt)
                    a = MF(ah[jj * 6 + kt], Bh[kt], a);
                *(f32x4*)&zb[l15][jt * 16 + quad * 4] = a;
            }
        }
        __syncthreads();

        // ---- L2 gates: thread = (row rg, cols jp,jp+1); b32 store ----
        {
            const f32x2 zi = *(const f32x2*)&zb[rg][jp];
            const f32x2 zf = *(const f32x2*)&zb[rg][64 + jp];
            const f32x2 zg = *(const f32x2*)&zb[rg][128 + jp];
            const f32x2 zo = *(const f32x2*)&zb[rg][192 + jp];
            f32x2 c = *(const f32x2*)&c23[rg][jp];
            unsigned hw = 0;
            #pragma unroll
            for (int k = 0; k < 2; ++k) {
                const float cc = sigm(zf[k]) * c[k] + sigm(zi[k]) * fmaxf(zg[k], 0.f);
                c[k] = cc;
                const float h = sigm(zo[k]) * fmaxf(cc, 0.f);
                hw |= ((unsigned)f2bf(h)) << (16 * k);
            }
            *(f32x2*)&c23[rg][jp] = c;
            *(unsigned*)&bU[rg][256 + jp] = hw;
        }
        // no trailing barrier: next-iter barrier1 covers hazards
    }
    __syncthreads();

    // ================= z3x = b3 + h2_final @ W3 (K=64 at col 256) =================
    {
        bf16x8 Bh[2];
        #pragma unroll
        for (int kt = 0; kt < 2; ++kt)
            Bh[kt] = *(const bf16x8*)&bU[l15][256 + kt * 32 + quad * 8];
        #pragma unroll
        for (int jj = 0; jj < 2; ++jj) {
            const int jt = 2 * wid + jj;
            f32x4 a = *(const f32x4*)&b3[jt * 16 + quad * 4];
            #pragma unroll
            for (int kt = 0; kt < 2; ++kt) {
                const bf16x8 ah = A[(FB_W3 + (jt * 2 + kt) * 2) * 64 + lane];
                a = MF(ah, Bh[kt], a);
            }
            *(f32x4*)&z3x[l15][jt * 16 + quad * 4] = a;
        }
    }
    __syncthreads();
    // re-zero activation plane + c-state for phase B
    {
        unsigned* p = (unsigned*)&bU[0][0];
        for (int i = tid; i < 16 * BSTR / 2; i += NTH) p[i] = 0u;
        float* q = &c23[0][0];
        for (int i = tid; i < 16 * 64; i += NTH) q[i] = 0.f;
        c4r[0] = c4r[1] = c4r[2] = c4r[3] = 0.f;
    }
    __syncthreads();

    // ================= Phase B =================
    for (int t = 0; t < TSEQ; ++t) {
        const int rb3 = (t & 1) * 64, wb3 = 64 - rb3;
        const int rb4 = 128 + (t & 1) * 128;
        const int wb4 = (rb4 == 128) ? 256 : 128;

        // ---- L3 MFMA (h3_old), acc init = 0 (z3x carries b3) ----
        {
            bf16x8 ah[4];
            #pragma unroll
            for (int jj = 0; jj < 2; ++jj)
                #pragma unroll
                for (int kt = 0; kt < 2; ++kt)
                    ah[jj * 2 + kt] = A[(FB_L3 + ((2 * wid + jj) * 2 + kt) * 2) * 64 + lane];
            bf16x8 Bh[2];
            #pragma unroll
            for (int kt = 0; kt < 2; ++kt)
                Bh[kt] = *(const bf16x8*)&bU[l15][rb3 + kt * 32 + quad * 8];
            #pragma unroll
            for (int jj = 0; jj < 2; ++jj) {
                const int jt = 2 * wid + jj;
                f32x4 a = {0.f, 0.f, 0.f, 0.f};
                #pragma unroll
                for (int kt = 0; kt < 2; ++kt)
                    a = MF(ah[jj * 2 + kt], Bh[kt], a);
                *(f32x4*)&zb[l15][jt * 16 + quad * 4] = a;
            }
        }
        __syncthreads();

        // ---- L3 gates (z = zb + z3x) + dense(t-1) into obuf ----
        {
            const f32x2 zi = *(const f32x2*)&zb[rg][jp]       + *(const f32x2*)&z3x[rg][jp];
            const f32x2 zf = *(const f32x2*)&zb[rg][64 + jp]  + *(const f32x2*)&z3x[rg][64 + jp];
            const f32x2 zg = *(const f32x2*)&zb[rg][128 + jp] + *(const f32x2*)&z3x[rg][128 + jp];
            const f32x2 zo = *(const f32x2*)&zb[rg][192 + jp] + *(const f32x2*)&z3x[rg][192 + jp];
            f32x2 c = *(const f32x2*)&c23[rg][jp];
            unsigned hw = 0;
            #pragma unroll
            for (int k = 0; k < 2; ++k) {
                const float cc = sigm(zf[k]) * c[k] + sigm(zi[k]) * fmaxf(zg[k], 0.f);
                c[k] = cc;
                const float h = sigm(zo[k]) * fmaxf(cc, 0.f);
                hw |= ((unsigned)f2bf(h)) << (16 * k);
            }
            *(f32x2*)&c23[rg][jp] = c;
            *(unsigned*)&bU[rg][wb3 + jp] = hw;

            if (t > 0) {  // dense for t-1: h4_{t-1} at rb4 (protected by barrier1)
                #pragma unroll
                for (int e = 0; e < 2; ++e) {
                    const int r = wid + 8 * e;
                    const float h0 = bf2f(bU[r][rb4 + lane]);
                    const float h1_ = bf2f(bU[r][rb4 + 64 + lane]);
                    float v = h0 * wd0 + h1_ * wd1;
                    v += __shfl_down(v, 32);
                    v += __shfl_down(v, 16);
                    v += __shfl_down(v, 8);
                    v += __shfl_down(v, 4);
                    v += __shfl_down(v, 2);
                    v += __shfl_down(v, 1);
                    if (lane == 0) obuf[r][t - 1] = v + bd0;
                }
            }
        }
        __syncthreads();

        // ---- L4: MFMA K=192 = [h3_new ; h4_old], acc init = b4; in-register gates ----
        {
            bf16x8 Bh[6];
            #pragma unroll
            for (int kt = 0; kt < 2; ++kt)
                Bh[kt] = *(const bf16x8*)&bU[l15][wb3 + kt * 32 + quad * 8];
            #pragma unroll
            for (int kt = 2; kt < 6; ++kt)
                Bh[kt] = *(const bf16x8*)&bU[l15][rb4 + (kt - 2) * 32 + quad * 8];
            bf16x8 ah[24];
            #pragma unroll
            for (int q = 0; q < 4; ++q)
                #pragma unroll
                for (int kt = 0; kt < 6; ++kt)
                    ah[q * 6 + kt] = A[(FB_L4 + ((wid + 8 * q) * 6 + kt) * 2) * 64 + lane];
            f32x4 acc[4];
            #pragma unroll
            for (int q = 0; q < 4; ++q) {
                f32x4 a = *(const f32x4*)&b4ls[(wid + 8 * q) * 16 + quad * 4];
                #pragma unroll
                for (int kt = 0; kt < 6; ++kt)
                    a = MF(ah[q * 6 + kt], Bh[kt], a);
                acc[q] = a;
            }
            s16x4 hv;
            #pragma unroll
            for (int g = 0; g < 4; ++g) {
                const float zi = acc[0][g];
                const float zf = acc[1][g];
                const float zg = acc[2][g];
                const float zo = acc[3][g];
                const float c = sigm(zf) * c4r[g] + sigm(zi) * fmaxf(zg, 0.f);
                c4r[g] = c;
                const float h = sigm(zo) * fmaxf(c, 0.f);
                hv[g] = (short)f2bf(h);
            }
            *(s16x4*)&bU[l15][wb4 + hcb] = hv;
        }
        // no trailing barrier: next-iter barrier1 covers h4/zb hazards
    }
    __syncthreads();
    // final dense: h4_{127} at col 128 (wb4 of t=127) -> obuf
    {
        #pragma unroll
        for (int e = 0; e < 2; ++e) {
            const int r = wid + 8 * e;
            const float h0 = bf2f(bU[r][128 + lane]);
            const float h1_ = bf2f(bU[r][128 + 64 + lane]);
            float v = h0 * wd0 + h1_ * wd1;
            v += __shfl_down(v, 32);
            v += __shfl_down(v, 16);
            v += __shfl_down(v, 8);
            v += __shfl_down(v, 4);
            v += __shfl_down(v, 2);
            v += __shfl_down(v, 1);
            if (lane == 0) obuf[r][127] = v + bd0;
        }
    }
    __syncthreads();
    // coalesced flush: 4 floats/thread
    {
        const int frow = tid >> 5;
        const int fcol = (tid & 31) * 4;
        *(f32x4*)&out[(r0 + frow) * TSEQ + fcol] = *(const f32x4*)&obuf[frow][fcol];
    }
}

// ---------------- fallback: round-0 fp32 kernel (known good, 4.8 ms) ----------------
#define FNT 512
#define FRPB 8
__global__ __launch_bounds__(FNT, 2) void lstm_stack_kernel(
    const float* __restrict__ x,
    const float* __restrict__ W1, const float* __restrict__ U1, const float* __restrict__ b1,
    const float* __restrict__ W2, const float* __restrict__ U2, const float* __restrict__ b2,
    const float* __restrict__ W3, const float* __restrict__ U3, const float* __restrict__ b3,
    const float* __restrict__ W4, const float* __restrict__ U4, const float* __restrict__ b4,
    const float* __restrict__ Wd, const float* __restrict__ bd,
    float* __restrict__ out)
{
    __shared__ float h1s[FRPB][128], c1s[FRPB][128];
    __shared__ float h2s[FRPB][64],  c2s[FRPB][64];
    __shared__ float h3s[FRPB][64],  c3s[FRPB][64];
    __shared__ float h4s[FRPB][128], c4s[FRPB][128];
    __shared__ float zbf[FRPB][512];
    __shared__ float z3xf[FRPB][256];
    __shared__ float xs[FRPB];

    const int tid = threadIdx.x;
    const int r0  = blockIdx.x * FRPB;
    const int jg  = tid & 255;
    const int grp = tid >> 8;
    const int rb  = grp * 4;

    {
        float* p1 = &h1s[0][0]; float* p2 = &c1s[0][0];
        float* p3 = &h4s[0][0]; float* p4 = &c4s[0][0];
        for (int i = tid; i < FRPB * 128; i += FNT) { p1[i]=0.f; p2[i]=0.f; p3[i]=0.f; p4[i]=0.f; }
        float* q1 = &h2s[0][0]; float* q2 = &c2s[0][0];
        float* q3 = &h3s[0][0]; float* q4 = &c3s[0][0];
        for (int i = tid; i < FRPB * 64; i += FNT) { q1[i]=0.f; q2[i]=0.f; q3[i]=0.f; q4[i]=0.f; }
    }
    __syncthreads();

    const float w1j = W1[tid];
    const float b1j = b1[tid];
    const float b2j = b2[jg];

    for (int t = 0; t < TSEQ; ++t) {
        if (tid < FRPB) xs[tid] = x[(r0 + tid) * TSEQ + t];
        __syncthreads();
        {
            float acc[FRPB];
            #pragma unroll
            for (int r = 0; r < FRPB; ++r) acc[r] = 0.f;
            const float* Uc = U1 + tid;
            #pragma unroll 4
            for (int k4 = 0; k4 < 32; ++k4) {
                const float u0 = Uc[(k4*4+0)*512];
                const float u1 = Uc[(k4*4+1)*512];
                const float u2 = Uc[(k4*4+2)*512];
                const float u3 = Uc[(k4*4+3)*512];
                #pragma unroll
                for (int r = 0; r < FRPB; ++r) {
                    const float4 h = ((const float4*)h1s[r])[k4];
                    acc[r] += h.x*u0 + h.y*u1 + h.z*u2 + h.w*u3;
                }
            }
            #pragma unroll
            for (int r = 0; r < FRPB; ++r) zbf[r][tid] = acc[r] + xs[r]*w1j + b1j;
        }
        __syncthreads();
        for (int e = tid; e < FRPB * 128; e += FNT) {
            const int r = e >> 7, hc = e & 127;
            const float zi = zbf[r][hc], zf = zbf[r][128+hc], zg = zbf[r][256+hc], zo = zbf[r][384+hc];
            const float c = sigm(zf)*c1s[r][hc] + sigm(zi)*fmaxf(zg, 0.f);
            c1s[r][hc] = c;
            h1s[r][hc] = sigm(zo)*fmaxf(c, 0.f);
        }
        __syncthreads();
        {
            float acc[4] = {0.f, 0.f, 0.f, 0.f};
            const float* Wc = W2 + jg;
            #pragma unroll 4
            for (int k4 = 0; k4 < 32; ++k4) {
                const float u0 = Wc[(k4*4+0)*256];
                const float u1 = Wc[(k4*4+1)*256];
                const float u2 = Wc[(k4*4+2)*256];
                const float u3 = Wc[(k4*4+3)*256];
                #pragma unroll
                for (int q = 0; q < 4; ++q) {
                    const float4 h = ((const float4*)h1s[rb+q])[k4];
                    acc[q] += h.x*u0 + h.y*u1 + h.z*u2 + h.w*u3;
                }
            }
            const float* Uc = U2 + jg;
            #pragma unroll 4
            for (int k4 = 0; k4 < 16; ++k4) {
                const float u0 = Uc[(k4*4+0)*256];
                const float u1 = Uc[(k4*4+1)*256];
                const float u2 = Uc[(k4*4+2)*256];
                const float u3 = Uc[(k4*4+3)*256];
                #pragma unroll
                for (int q = 0; q < 4; ++q) {
                    const float4 h = ((const float4*)h2s[rb+q])[k4];
                    acc[q] += h.x*u0 + h.y*u1 + h.z*u2 + h.w*u3;
                }
            }
            #pragma unroll
            for (int q = 0; q < 4; ++q) zbf[rb+q][jg] = acc[q] + b2j;
        }
        __syncthreads();
        {
            const int r = tid >> 6, hc = tid & 63;
            const float zi = zbf[r][hc], zf = zbf[r][64+hc], zg = zbf[r][128+hc], zo = zbf[r][192+hc];
            const float c = sigm(zf)*c2s[r][hc] + sigm(zi)*fmaxf(zg, 0.f);
            c2s[r][hc] = c;
            h2s[r][hc] = sigm(zo)*fmaxf(c, 0.f);
        }
        __syncthreads();
    }
    {
        float acc[4] = {0.f, 0.f, 0.f, 0.f};
        const float* Wc = W3 + jg;
        #pragma unroll 4
        for (int k4 = 0; k4 < 16; ++k4) {
            const float u0 = Wc[(k4*4+0)*256];
            const float u1 = Wc[(k4*4+1)*256];
            const float u2 = Wc[(k4*4+2)*256];
            const float u3 = Wc[(k4*4+3)*256];
            #pragma unroll
            for (int q = 0; q < 4; ++q) {
                const float4 h = ((const float4*)h2s[rb+q])[k4];
                acc[q] += h.x*u0 + h.y*u1 + h.z*u2 + h.w*u3;
            }
        }
        const float b3j = b3[jg];
        #pragma unroll
        for (int q = 0; q < 4; ++q) z3xf[rb+q][jg] = acc[q] + b3j;
    }
    __syncthreads();

    const float b4j = b4[tid];
    const float wd0 = Wd[tid & 63];
    const float wd1 = Wd[64 + (tid & 63)];
    const float bd0 = bd[0];

    for (int t = 0; t < TSEQ; ++t) {
        {
            float acc[4];
            #pragma unroll
            for (int q = 0; q < 4; ++q) acc[q] = z3xf[rb+q][jg];
            const float* Uc = U3 + jg;
            #pragma unroll 4
            for (int k4 = 0; k4 < 16; ++k4) {
                const float u0 = Uc[(k4*4+0)*256];
                const float u1 = Uc[(k4*4+1)*256];
                const float u2 = Uc[(k4*4+2)*256];
                const float u3 = Uc[(k4*4+3)*256];
                #pragma unroll
                for (int q = 0; q < 4; ++q) {
                    const float4 h = ((const float4*)h3s[rb+q])[k4];
                    acc[q] += h.x*u0 + h.y*u1 + h.z*u2 + h.w*u3;
                }
            }
            #pragma unroll
            for (int q = 0; q < 4; ++q) zbf[rb+q][jg] = acc[q];
        }
        __syncthreads();
        {
            const int r = tid >> 6, hc = tid & 63;
            const float zi = zbf[r][hc], zf = zbf[r][64+hc], zg = zbf[r][128+hc], zo = zbf[r][192+hc];
            const float c = sigm(zf)*c3s[r][hc] + sigm(zi)*fmaxf(zg, 0.f);
            c3s[r][hc] = c;
            h3s[r][hc] = sigm(zo)*fmaxf(c, 0.f);
        }
        __syncthreads();
        {
            float acc[FRPB];
            #pragma unroll
            for (int r = 0; r < FRPB; ++r) acc[r] = 0.f;
            const float* Wc = W4 + tid;
            #pragma unroll 4
            for (int k4 = 0; k4 < 16; ++k4) {
                const float u0 = Wc[(k4*4+0)*512];
                const float u1 = Wc[(k4*4+1)*512];
                const float u2 = Wc[(k4*4+2)*512];
                const float u3 = Wc[(k4*4+3)*512];
                #pragma unroll
                for (int r = 0; r < FRPB; ++r) {
                    const float4 h = ((const float4*)h3s[r])[k4];
                    acc[r] += h.x*u0 + h.y*u1 + h.z*u2 + h.w*u3;
                }
            }
            const float* Uc = U4 + tid;
            #pragma unroll 4
            for (int k4 = 0; k4 < 32; ++k4) {
                const float u0 = Uc[(k4*4+0)*512];
                const float u1 = Uc[(k4*4+1)*512];
                const float u2 = Uc[(k4*4+2)*512];
                const float u3 = Uc[(k4*4+3)*512];
                #pragma unroll
                for (int r = 0; r < FRPB; ++r) {
                    const float4 h = ((const float4*)h4s[r])[k4];
                    acc[r] += h.x*u0 + h.y*u1 + h.z*u2 + h.w*u3;
                }
            }
            #pragma unroll
            for (int r = 0; r < FRPB; ++r) zbf[r][tid] = acc[r] + b4j;
        }
        __syncthreads();
        for (int e = tid; e < FRPB * 128; e += FNT) {
            const int r = e >> 7, hc = e & 127;
            const float zi = zbf[r][hc], zf = zbf[r][128+hc], zg = zbf[r][256+hc], zo = zbf[r][384+hc];
            const float c = sigm(zf)*c4s[r][hc] + sigm(zi)*fmaxf(zg, 0.f);
            c4s[r][hc] = c;
            h4s[r][hc] = sigm(zo)*fmaxf(c, 0.f);
        }
        __syncthreads();
        {
            const int wv = tid >> 6, ln = tid & 63;
            float v = h4s[wv][ln]*wd0 + h4s[wv][64+ln]*wd1;
            v += __shfl_down(v, 32, 64);
            v += __shfl_down(v, 16, 64);
            v += __shfl_down(v,  8, 64);
            v += __shfl_down(v,  4, 64);
            v += __shfl_down(v,  2, 64);
            v += __shfl_down(v,  1, 64);
            if (ln == 0) out[(r0 + wv) * TSEQ + t] = v + bd0;
        }
    }
}

extern "C" void kernel_launch(void* const* d_in, const int* in_sizes, int n_in,
                              void* d_out, int out_size, void* d_ws, size_t ws_size,
                              hipStream_t stream) {
    const float* x  = (const float*)d_in[0];
    const float* W1 = (const float*)d_in[1];
    const float* U1 = (const float*)d_in[2];
    const float* b1 = (const float*)d_in[3];
    const float* W2 = (const float*)d_in[4];
    const float* U2 = (const float*)d_in[5];
    const float* b2 = (const float*)d_in[6];
    const float* W3 = (const float*)d_in[7];
    const float* U3 = (const float*)d_in[8];
    const float* b3 = (const float*)d_in[9];
    const float* W4 = (const float*)d_in[10];
    const float* U4 = (const float*)d_in[11];
    const float* b4 = (const float*)d_in[12];
    const float* Wd = (const float*)d_in[13];
    const float* bd = (const float*)d_in[14];
    float* out = (float*)d_out;

    if (ws_size >= (size_t)WS_NEEDED) {
        ushort_t* wsp = (ushort_t*)d_ws;
        pack_weights<<<dim3(WS_FRAGS), dim3(64), 0, stream>>>(U1, W2, U2, U3, W4, U4, W3, wsp);
        lstm_mfma_kernel<<<dim3(2048 / 16), dim3(NTH), 0, stream>>>(
            x, W1, b1, b2, b3, b4, Wd, bd, wsp, out);
    } else {
        lstm_stack_kernel<<<dim3(2048 / FRPB), dim3(FNT), 0, stream>>>(
            x, W1, U1, b1, W2, U2, b2, W3, U3, b3, W4, U4, b4, Wd, bd, out);
    }
}